// Round 13
// baseline (1963.740 us; speedup 1.0000x reference)
//
#include <hip/hip_runtime.h>

// ---------------- sizes / workspace layout (floats) ----------------
constexpr int BB   = 16;
constexpr int VS   = BB*3*32*32;     // 49152
constexpr int M1N  = BB*64*32*32;    // 1048576
constexpr int O1PN = BB*64*18*20;    // 368640 (padded 16x16 interior)
constexpr int M2N  = BB*128*16*16;   // 524288
constexpr int O2PN = BB*128*18*20;   // 737280
constexpr int M3N  = M2N;
constexpr int FBN  = BB*8192;        // 131072
constexpr int M4N  = BB*1024;
constexpr int M5N  = BB*1024;

constexpr int off_v   = 0;                 // x2 ping-pong
constexpr int off_s   = off_v   + 2*VS;
constexpr int off_m1  = off_s   + 2*VS;
constexpr int off_o1p = off_m1  + M1N;     // x2
constexpr int off_m2  = off_o1p + 2*O1PN;
constexpr int off_o2p = off_m2  + M2N;     // x2
constexpr int off_m3  = off_o2p + 2*O2PN;
constexpr int off_f   = off_m3  + M3N;     // x2
constexpr int off_m4  = off_f   + 2*FBN;
constexpr int off_o4  = off_m4  + M4N;     // x2
constexpr int off_m5  = off_o4  + 2*M4N;
constexpr int off_o5  = off_m5  + M5N;     // x2
constexpr int off_w1r = off_o5  + 2*M5N;   // zero-region ends here
constexpr int W1RN = 64*3*12;              // conv1: [co][ci][12]
// conv2/conv3: compact co-pair records [cog8][pair8][ci][20]
constexpr int off_w2r = off_w1r + W1RN;
constexpr int W2RN = 8*8*64*20;            // 81920
constexpr int off_w3r = off_w2r + W2RN;
constexpr int W3RN = 8*8*128*20;           // 163840
constexpr int TOTF = off_w3r + W3RN;

__device__ __forceinline__ float4 ld4(const float* p){ return *reinterpret_cast<const float4*>(p); }
__device__ __forceinline__ float2 ld2(const float* p){ return *reinterpret_cast<const float2*>(p); }
__device__ __forceinline__ float spk(float m){ return m > 1.0f ? 1.0f : 0.0f; }

// async global->LDS, 16B per lane; LDS dest linear per wave (base + lane*16)
__device__ __forceinline__ void gll16(const float* g, float* l) {
    __builtin_amdgcn_global_load_lds(
        (const __attribute__((address_space(1))) unsigned int*)g,
        (__attribute__((address_space(3))) unsigned int*)(unsigned int)(unsigned long long)l,
        16, 0, 0);
}

// ---------------- init: zero state, repack conv weights ----------------
__global__ __launch_bounds__(256) void init_k(const float* __restrict__ W1,
                                              const float* __restrict__ W2,
                                              const float* __restrict__ W3,
                                              float* __restrict__ ws,
                                              float* __restrict__ out) {
    int i0 = blockIdx.x*256 + threadIdx.x;
    int stride = gridDim.x*256;
    for (int p = i0; p < TOTF; p += stride) {
        float val = 0.0f;
        if (p >= off_w1r) {
            if (p < off_w2r) {               // conv1 [co][ci][12]
                int l = p - off_w1r, q = l/12, r = l%12;
                int dx = r & 3, dy = r >> 2;
                val = (dx < 3) ? W1[q*9 + dy*3 + dx] : 0.0f;
            } else if (p < off_w3r) {        // conv2 pair records
                int l = p - off_w2r;
                int cog = l / 10240, rem = l % 10240;
                int pr = rem / 1280, rem2 = rem % 1280;
                int ci = rem2 / 20, k = rem2 % 20;
                if (k < 18) {
                    int co = cog*16 + pr*2 + (k >= 9 ? 1 : 0);
                    int kk = k >= 9 ? k - 9 : k;
                    val = W2[(co*64 + ci)*9 + kk];
                }
            } else {                         // conv3 pair records
                int l = p - off_w3r;
                int cog = l / 20480, rem = l % 20480;
                int pr = rem / 2560, rem2 = rem % 2560;
                int ci = rem2 / 20, k = rem2 % 20;
                if (k < 18) {
                    int co = cog*16 + pr*2 + (k >= 9 ? 1 : 0);
                    int kk = k >= 9 ? k - 9 : k;
                    val = W3[(co*128 + ci)*9 + kk];
                }
            }
        }
        ws[p] = val;
    }
    if (i0 < 160) out[i0] = 0.0f;
}

// ---- conv macros: weights 2 co packed in 20 floats; outputs 2co x 2y x 4x ----
#define CVW_LOAD(W, WQ) do {                                                   \
    _Pragma("unroll") for (int q_ = 0; q_ < 5; ++q_) W[q_] = ld4((WQ) + q_*4); } while(0)

#define CV4_FMA(Iu, Iv, W) do {                                                \
    float rv[4][6];                                                            \
    _Pragma("unroll") for (int r_ = 0; r_ < 4; ++r_) {                         \
        rv[r_][0]=Iu[r_].x; rv[r_][1]=Iu[r_].y; rv[r_][2]=Iu[r_].z;            \
        rv[r_][3]=Iu[r_].w; rv[r_][4]=Iv[r_].x; rv[r_][5]=Iv[r_].y; }          \
    float wd[2][9] = {{W[0].x,W[0].y,W[0].z,W[0].w,W[1].x,W[1].y,W[1].z,W[1].w,W[2].x}, \
                      {W[2].y,W[2].z,W[2].w,W[3].x,W[3].y,W[3].z,W[3].w,W[4].x,W[4].y}}; \
    _Pragma("unroll") for (int cc_ = 0; cc_ < 2; ++cc_)                        \
      _Pragma("unroll") for (int iy_ = 0; iy_ < 2; ++iy_)                      \
        _Pragma("unroll") for (int dy_ = 0; dy_ < 3; ++dy_)                    \
          _Pragma("unroll") for (int dx_ = 0; dx_ < 3; ++dx_) {                \
            float wv_ = wd[cc_][dy_*3+dx_];                                    \
            _Pragma("unroll") for (int p_ = 0; p_ < 4; ++p_)                   \
              acc[cc_][iy_][p_] += rv[iy_+dy_][p_+dx_]*wv_; } } while(0)

// LDS stencil read: 4 rows (28-float stride), 6 floats each
#define CVL_READ(Iu, Iv, P) do {                                               \
    _Pragma("unroll") for (int r_ = 0; r_ < 4; ++r_) {                         \
        Iu[r_] = ld4((P) + r_*28); Iv[r_] = ld2((P) + r_*28 + 4); } } while(0)

// stage one 8-plane chunk: 1008 16B-chunks, linear LDS dest, computed src
#define CV_STAGE(BUF, CH) do {                                                 \
    _Pragma("unroll") for (int k_ = 0; k_ < 4; ++k_) {                         \
        if (k_*256 + tid < 1008)                                               \
            gll16(gip + (CH)*2880 + ssrc[k_], sh + (BUF)*4032 + sdst[k_]);     \
    } } while(0)

// ---------------- one fused timestep ----------------
// bid map (round-8 order, best measured): [0,128) conv3 | [128,256) conv2
//          [256,384) fc1 | [384,640) enc+conv1 | [640,896) fc2 | 896 fc3
__global__ __launch_bounds__(256) void step_k(const float* __restrict__ x,
                                              const float* __restrict__ L1,
                                              const float* __restrict__ L2,
                                              const float* __restrict__ L3,
                                              float* __restrict__ ws,
                                              float* __restrict__ out,
                                              int t) {
    const int rp = t & 1, wp = rp ^ 1;
    const int bid = blockIdx.x, tid = threadIdx.x;
    __shared__ __align__(16) float sh[8064];   // 32.3KB: conv in-dbuf 2x4032 | fc1 4224 | fc2 4608

    if (bid < 256) {
        // ---- conv3 [0,128) / conv2 [128,256): inputs staged via gll16 into 28-stride LDS ----
        const bool is3 = bid < 128;
        int bb = is3 ? bid : bid - 128;
        int b = bb >> 3, cog = bb & 7;
        int cl = tid >> 5, rest = tid & 31, rpair = rest >> 2, cg = rest & 3;
        int y0 = rpair*2, x0 = cg*4;
        int co = cog*16 + cl*2;
        const int NCI = is3 ? 128 : 64;
        const float* gip = is3 ? (ws + off_o2p + rp*O2PN + b*128*360)
                               : (ws + off_o1p + rp*O1PN + b*64*360);
        const float* wpt = is3 ? (ws + off_w3r + (cog*8 + cl)*128*20)
                               : (ws + off_w2r + (cog*8 + cl)*64*20);
        // staging slot precompute: chunk c -> (u=c/126, r=(c%126)/7, j=(c%126)%7)
        int ssrc[4], sdst[4];
        #pragma unroll
        for (int k = 0; k < 4; ++k) {
            int c = k*256 + tid;
            int u = c/126, rem = c - u*126, r = rem/7, j = rem - r*7;
            ssrc[k] = u*360 + (j < 5 ? 20*r + 4*j : 0);
            sdst[k] = c*4;
        }
        float acc[2][2][4] = {};
        float4 WA[5], WB[5];
        CVW_LOAD(WA, wpt);
        CVW_LOAD(WB, wpt + 20);
        CV_STAGE(0, 0);
        __syncthreads();                     // barrier drains vmcnt -> stage 0 landed
        const int NCH = NCI >> 3;
        #pragma unroll 1
        for (int ch = 0; ch < NCH; ++ch) {
            if (ch + 1 < NCH) CV_STAGE((ch+1)&1, ch+1);   // overlaps with this chunk's FMA
            const float* lb = sh + (ch&1)*4032 + y0*28 + x0;
            #pragma unroll
            for (int u = 0; u < 8; u += 2) {              // FULL unroll: deeper read/FMA pipeline
                int ci = ch*8 + u;
                {
                    float4 IAu[4]; float2 IAv[4];
                    CVL_READ(IAu, IAv, lb + u*504);
                    CV4_FMA(IAu, IAv, WA);
                    if (ci + 2 < NCI) CVW_LOAD(WA, wpt + (ci+2)*20);
                }
                {
                    float4 IBu[4]; float2 IBv[4];
                    CVL_READ(IBu, IBv, lb + u*504 + 504);
                    CV4_FMA(IBu, IBv, WB);
                    if (ci + 3 < NCI) CVW_LOAD(WB, wpt + (ci+3)*20);
                }
            }
            __syncthreads();                 // all waves done with buf[ch&1]; stage(ch+1) drained
        }
        if (is3) {
            #pragma unroll
            for (int cc = 0; cc < 2; ++cc) {
                float sp[2][4];
                #pragma unroll
                for (int iy = 0; iy < 2; ++iy)
                    #pragma unroll
                    for (int p = 0; p < 4; ++p) {
                        int gm = off_m3 + ((b*128 + co + cc)*16 + y0 + iy)*16 + x0 + p;
                        float m = ws[gm], o = spk(m);
                        float mn = m + acc[cc][iy][p] - o;
                        ws[gm] = mn;
                        sp[iy][p] = spk(mn);
                    }
                int fbase = off_f + wp*FBN + b*8192 + (co + cc)*64 + (y0>>1)*8 + (x0>>1);
                ws[fbase+0] = (sp[0][0]+sp[0][1]+sp[1][0]+sp[1][1])*0.25f;
                ws[fbase+1] = (sp[0][2]+sp[0][3]+sp[1][2]+sp[1][3])*0.25f;
            }
        } else {
            #pragma unroll
            for (int cc = 0; cc < 2; ++cc) {
                #pragma unroll
                for (int iy = 0; iy < 2; ++iy) {
                    int mbase = off_m2 + ((b*128 + co + cc)*16 + y0 + iy)*16 + x0;
                    int obase = off_o2p + wp*O2PN + ((b*128 + co + cc)*18 + y0 + iy + 1)*20 + x0 + 1;
                    #pragma unroll
                    for (int p = 0; p < 4; ++p) {
                        float m = ws[mbase+p], o = spk(m);
                        float mn = m + acc[cc][iy][p] - o;
                        ws[mbase+p] = mn;
                        ws[obase+p] = spk(mn);
                    }
                }
            }
        }
    } else if (bid < 384) {
        // ---- fc1 8192->1024 + LIF(m4): barrier-free K-loop, acts from L2, 2-deep W prefetch ----
        int jb = bid - 256;
        int w = tid >> 6, l = tid & 63;
        const float* fp = ws + off_f + rp*FBN;
        const float* wb = L1 + (jb*8 + w*2)*8192;
        float acc[2][16] = {};
        float4 wA[2], wB[2];
        #pragma unroll
        for (int jj = 0; jj < 2; ++jj) {
            wA[jj] = ld4(wb + jj*8192 + l*4);
            wB[jj] = ld4(wb + jj*8192 + 256 + l*4);
        }
        for (int c = 0; c < 32; ++c) {
            const float* av = fp + c*256 + l*4;
            #pragma unroll
            for (int b = 0; b < 16; ++b) {
                float4 fv = ld4(av + b*8192);
                acc[0][b] += wA[0].x*fv.x + wA[0].y*fv.y + wA[0].z*fv.z + wA[0].w*fv.w;
                acc[1][b] += wA[1].x*fv.x + wA[1].y*fv.y + wA[1].z*fv.z + wA[1].w*fv.w;
            }
            wA[0] = wB[0]; wA[1] = wB[1];
            if (c < 30) {
                wB[0] = ld4(wb + (c+2)*256 + l*4);
                wB[1] = ld4(wb + 8192 + (c+2)*256 + l*4);
            }
        }
        #pragma unroll
        for (int jj = 0; jj < 2; ++jj)
            #pragma unroll
            for (int b = 0; b < 16; ++b) acc[jj][b] += __shfl_xor(acc[jj][b], 1);
        float* rg = sh + w*1056;
        if ((l & 1) == 0) {
            #pragma unroll
            for (int jj = 0; jj < 2; ++jj)
                #pragma unroll
                for (int b = 0; b < 16; ++b) rg[(l>>1)*33 + jj*16 + b] = acc[jj][b];
        }
        __syncthreads();
        if (tid < 128) {
            int w2 = tid >> 5, r = tid & 31, jj = r >> 4, b = r & 15;
            const float* rg2 = sh + w2*1056;
            float sum = 0.0f;
            #pragma unroll
            for (int l2 = 0; l2 < 32; ++l2) sum += rg2[l2*33 + r];
            int j = jb*8 + w2*2 + jj;
            int gi = off_m4 + b*1024 + j;
            float m = ws[gi], o = spk(m);
            float mn = m + sum - o;
            ws[gi] = mn;
            ws[off_o4 + wp*M4N + b*1024 + j] = spk(mn);
        }
    } else if (bid < 640) {
        // ---- encoder (redundant) + conv1 + LIF(m1) + pooled next-spike ----
        int bb = bid - 384;
        int b = bb >> 4, tile = bb & 15;
        int ty = tile >> 2, tx = tile & 3;
        int y0 = ty*8, x0 = tx*8;
        const float* vin  = ws + off_v + rp*VS + b*3072;
        float*       vout = ws + off_v + wp*VS + b*3072;
        const float* sin_ = ws + off_s + rp*VS + b*3072;
        float*       sout = ws + off_s + wp*VS + b*3072;
        const float* xin  = x + b*3072;
        float* sl = sh; // [3][10][12]
        for (int idx = tid; idx < 300; idx += 256) {
            int ci = idx/100, r2 = idx%100, rr = r2/10, cc = r2%10;
            int yy = y0 - 1 + rr, xx = x0 - 1 + cc;
            float sv = 0.0f;
            if ((unsigned)yy < 32u && (unsigned)xx < 32u) {
                int g = ci*1024 + yy*32 + xx;
                float vn = vin[g] + xin[g] - sin_[g];
                sv = vn > 1.0f ? 1.0f : 0.0f;
                if (yy >= y0 && yy < y0+8 && xx >= x0 && xx < x0+8) { vout[g] = vn; sout[g] = sv; }
            }
            sl[(ci*10 + rr)*12 + cc] = sv;
        }
        __syncthreads();
        int tl = tid & 15, cog = tid >> 4;
        int py = (tl >> 2)*2, px = (tl & 3)*2;
        for (int cl = 0; cl < 4; ++cl) {
            int co = cog*4 + cl;
            const float* wtp = ws + off_w1r + co*36;
            float a00=0,a01=0,a10=0,a11=0;
            #pragma unroll
            for (int ci = 0; ci < 3; ++ci) {
                float4 w0 = ld4(wtp + ci*12), w1 = ld4(wtp + ci*12 + 4), w2 = ld4(wtp + ci*12 + 8);
                float wdl[3][3] = {{w0.x,w0.y,w0.z},{w1.x,w1.y,w1.z},{w2.x,w2.y,w2.z}};
                #pragma unroll
                for (int dy = 0; dy < 3; ++dy)
                    #pragma unroll
                    for (int dx = 0; dx < 3; ++dx) {
                        float wvv = wdl[dy][dx];
                        const float* rsl = sl + (ci*10 + py + dy)*12 + px + dx;
                        a00 += rsl[0]  * wvv; a01 += rsl[1]  * wvv;
                        a10 += rsl[12] * wvv; a11 += rsl[13] * wvv;
                    }
            }
            int gy = y0 + py, gx = x0 + px;
            float accs[2][2] = {{a00,a01},{a10,a11}};
            float pooled = 0.0f;
            #pragma unroll
            for (int iy = 0; iy < 2; ++iy)
                #pragma unroll
                for (int ix = 0; ix < 2; ++ix) {
                    int gm = off_m1 + ((b*64 + co)*32 + gy + iy)*32 + gx + ix;
                    float m = ws[gm], o = spk(m);
                    float mn = m + accs[iy][ix] - o;
                    ws[gm] = mn;
                    pooled += spk(mn);
                }
            ws[off_o1p + wp*O1PN + ((b*64 + co)*18 + (gy>>1) + 1)*20 + (gx>>1) + 1] = pooled*0.25f;
        }
    } else if (bid < 896) {
        // ---- fc2 1024->1024 + LIF(m5); 256 blocks x 4 cols, 64-lane K-split ----
        int jb = bid - 640;
        int jg = tid >> 6, l = tid & 63;
        int j  = jb*4 + jg;
        const float* op = ws + off_o4 + rp*M4N;
        const float* wr = L2 + j*1024;
        float acc[16] = {};
        float4 wv[4];
        #pragma unroll
        for (int u = 0; u < 4; ++u) wv[u] = ld4(wr + u*256 + l*4);
        #pragma unroll
        for (int u = 0; u < 4; ++u) {
            int k = u*256 + l*4;
            #pragma unroll
            for (int b = 0; b < 16; ++b) {
                float4 fv = ld4(op + b*1024 + k);
                acc[b] += wv[u].x*fv.x + wv[u].y*fv.y + wv[u].z*fv.z + wv[u].w*fv.w;
            }
        }
        int r = jg*64 + l;
        #pragma unroll
        for (int b = 0; b < 16; ++b) sh[r*17 + b] = acc[b];
        __syncthreads();
        {
            int p = tid >> 2, q = tid & 3;
            float s2 = 0.0f;
            int rb2 = (p >> 4)*64 + q*16, col = p & 15;
            #pragma unroll
            for (int t2 = 0; t2 < 16; ++t2) s2 += sh[(rb2 + t2)*17 + col];
            sh[4352 + tid] = s2;
        }
        __syncthreads();
        if (tid < 64) {
            float sum = sh[4352 + tid*4] + sh[4352 + tid*4 + 1]
                      + sh[4352 + tid*4 + 2] + sh[4352 + tid*4 + 3];
            int jg2 = tid >> 4, b = tid & 15;
            int jj = jb*4 + jg2;
            int gi = off_m5 + b*1024 + jj;
            float m = ws[gi], o = spk(m);
            float mn = m + sum - o;
            ws[gi] = mn;
            ws[off_o5 + wp*M5N + b*1024 + jj] = spk(mn);
        }
    } else {
        // ---- fc3 1024->10, accumulate output membrane ----
        if (tid < 160) {
            int b = tid/10, c = tid - b*10;
            const float* op = ws + off_o5 + rp*M5N + b*1024;
            const float* wr = L3 + c*1024;
            float sum = 0.0f;
            for (int k = 0; k < 1024; k += 4) {
                float4 a = ld4(op + k), wvv = ld4(wr + k);
                sum += a.x*wvv.x + a.y*wvv.y + a.z*wvv.z + a.w*wvv.w;
            }
            out[b*10 + c] += sum;
        }
    }
}

extern "C" void kernel_launch(void* const* d_in, const int* in_sizes, int n_in,
                              void* d_out, int out_size, void* d_ws, size_t ws_size,
                              hipStream_t stream) {
    const float* x  = (const float*)d_in[0];
    const float* W1 = (const float*)d_in[1];
    const float* W2 = (const float*)d_in[2];
    const float* W3 = (const float*)d_in[3];
    const float* L1 = (const float*)d_in[4];
    const float* L2 = (const float*)d_in[5];
    const float* L3 = (const float*)d_in[6];
    float* out = (float*)d_out;
    float* ws  = (float*)d_ws;

    init_k<<<1024, 256, 0, stream>>>(W1, W2, W3, ws, out);
    for (int t = 0; t < 20; ++t)
        step_k<<<897, 256, 0, stream>>>(x, L1, L2, L3, ws, out, t);
}

// Round 14
// 1278.647 us; speedup vs baseline: 1.5358x; 1.5358x over previous
//
#include <hip/hip_runtime.h>

// ---------------- sizes / workspace layout (floats) ----------------
constexpr int BB   = 16;
constexpr int VS   = BB*3*32*32;     // 49152
constexpr int M1N  = BB*64*32*32;    // 1048576
constexpr int O1PN = BB*64*18*20;    // 368640 (padded 16x16 interior)
constexpr int M2N  = BB*128*16*16;   // 524288
constexpr int O2PN = BB*128*18*20;   // 737280
constexpr int M3N  = M2N;
constexpr int FBN  = BB*8192;        // 131072
constexpr int M4N  = BB*1024;
constexpr int M5N  = BB*1024;

constexpr int off_v   = 0;                 // x2 ping-pong
constexpr int off_s   = off_v   + 2*VS;
constexpr int off_m1  = off_s   + 2*VS;
constexpr int off_o1p = off_m1  + M1N;     // x2
constexpr int off_m2  = off_o1p + 2*O1PN;
constexpr int off_o2p = off_m2  + M2N;     // x2
constexpr int off_m3  = off_o2p + 2*O2PN;
constexpr int off_f   = off_m3  + M3N;     // x2
constexpr int off_m4  = off_f   + 2*FBN;
constexpr int off_o4  = off_m4  + M4N;     // x2
constexpr int off_m5  = off_o4  + 2*M4N;
constexpr int off_o5  = off_m5  + M5N;     // x2
constexpr int off_w1r = off_o5  + 2*M5N;   // zero-region ends here
constexpr int W1RN = 64*3*12;              // conv1: [co][ci][12]
// conv2/conv3: compact co-pair records [cog8][pair8][ci][20]
constexpr int off_w2r = off_w1r + W1RN;
constexpr int W2RN = 8*8*64*20;            // 81920
constexpr int off_w3r = off_w2r + W2RN;
constexpr int W3RN = 8*8*128*20;           // 163840
constexpr int TOTF = off_w3r + W3RN;

__device__ __forceinline__ float4 ld4(const float* p){ return *reinterpret_cast<const float4*>(p); }
__device__ __forceinline__ float2 ld2(const float* p){ return *reinterpret_cast<const float2*>(p); }
__device__ __forceinline__ float spk(float m){ return m > 1.0f ? 1.0f : 0.0f; }

// async global->LDS, 16B per lane; LDS dest linear per wave (base + lane*16)
__device__ __forceinline__ void gll16(const float* g, float* l) {
    __builtin_amdgcn_global_load_lds(
        (const __attribute__((address_space(1))) unsigned int*)g,
        (__attribute__((address_space(3))) unsigned int*)(unsigned int)(unsigned long long)l,
        16, 0, 0);
}

// ---------------- init: zero state, repack conv weights ----------------
__global__ __launch_bounds__(256) void init_k(const float* __restrict__ W1,
                                              const float* __restrict__ W2,
                                              const float* __restrict__ W3,
                                              float* __restrict__ ws,
                                              float* __restrict__ out) {
    int i0 = blockIdx.x*256 + threadIdx.x;
    int stride = gridDim.x*256;
    for (int p = i0; p < TOTF; p += stride) {
        float val = 0.0f;
        if (p >= off_w1r) {
            if (p < off_w2r) {               // conv1 [co][ci][12]
                int l = p - off_w1r, q = l/12, r = l%12;
                int dx = r & 3, dy = r >> 2;
                val = (dx < 3) ? W1[q*9 + dy*3 + dx] : 0.0f;
            } else if (p < off_w3r) {        // conv2 pair records
                int l = p - off_w2r;
                int cog = l / 10240, rem = l % 10240;
                int pr = rem / 1280, rem2 = rem % 1280;
                int ci = rem2 / 20, k = rem2 % 20;
                if (k < 18) {
                    int co = cog*16 + pr*2 + (k >= 9 ? 1 : 0);
                    int kk = k >= 9 ? k - 9 : k;
                    val = W2[(co*64 + ci)*9 + kk];
                }
            } else {                         // conv3 pair records
                int l = p - off_w3r;
                int cog = l / 20480, rem = l % 20480;
                int pr = rem / 2560, rem2 = rem % 2560;
                int ci = rem2 / 20, k = rem2 % 20;
                if (k < 18) {
                    int co = cog*16 + pr*2 + (k >= 9 ? 1 : 0);
                    int kk = k >= 9 ? k - 9 : k;
                    val = W3[(co*128 + ci)*9 + kk];
                }
            }
        }
        ws[p] = val;
    }
    if (i0 < 160) out[i0] = 0.0f;
}

// ---- conv macros: weights 2 co packed in 20 floats; outputs 2co x 2y x 4x ----
#define CVW_LOAD(W, WQ) do {                                                   \
    _Pragma("unroll") for (int q_ = 0; q_ < 5; ++q_) W[q_] = ld4((WQ) + q_*4); } while(0)

#define CV4_FMA(Iu, Iv, W) do {                                                \
    float rv[4][6];                                                            \
    _Pragma("unroll") for (int r_ = 0; r_ < 4; ++r_) {                         \
        rv[r_][0]=Iu[r_].x; rv[r_][1]=Iu[r_].y; rv[r_][2]=Iu[r_].z;            \
        rv[r_][3]=Iu[r_].w; rv[r_][4]=Iv[r_].x; rv[r_][5]=Iv[r_].y; }          \
    float wd[2][9] = {{W[0].x,W[0].y,W[0].z,W[0].w,W[1].x,W[1].y,W[1].z,W[1].w,W[2].x}, \
                      {W[2].y,W[2].z,W[2].w,W[3].x,W[3].y,W[3].z,W[3].w,W[4].x,W[4].y}}; \
    _Pragma("unroll") for (int cc_ = 0; cc_ < 2; ++cc_)                        \
      _Pragma("unroll") for (int iy_ = 0; iy_ < 2; ++iy_)                      \
        _Pragma("unroll") for (int dy_ = 0; dy_ < 3; ++dy_)                    \
          _Pragma("unroll") for (int dx_ = 0; dx_ < 3; ++dx_) {                \
            float wv_ = wd[cc_][dy_*3+dx_];                                    \
            _Pragma("unroll") for (int p_ = 0; p_ < 4; ++p_)                   \
              acc[cc_][iy_][p_] += rv[iy_+dy_][p_+dx_]*wv_; } } while(0)

// LDS stencil read: 4 rows (28-float stride), 6 floats each
#define CVL_READ(Iu, Iv, P) do {                                               \
    _Pragma("unroll") for (int r_ = 0; r_ < 4; ++r_) {                         \
        Iu[r_] = ld4((P) + r_*28); Iv[r_] = ld2((P) + r_*28 + 4); } } while(0)

// stage one 8-plane chunk: 1008 16B-chunks, linear LDS dest, computed src
#define CV_STAGE(BUF, CH) do {                                                 \
    _Pragma("unroll") for (int k_ = 0; k_ < 4; ++k_) {                         \
        if (k_*256 + tid < 1008)                                               \
            gll16(gip + (CH)*2880 + ssrc[k_], sh + (BUF)*4032 + sdst[k_]);     \
    } } while(0)

// ---------------- one fused timestep ----------------
// bid map (round-8 order, best measured): [0,128) conv3 | [128,256) conv2
//          [256,384) fc1 | [384,640) enc+conv1 | [640,896) fc2 | 896 fc3
__global__ __launch_bounds__(256) void step_k(const float* __restrict__ x,
                                              const float* __restrict__ L1,
                                              const float* __restrict__ L2,
                                              const float* __restrict__ L3,
                                              float* __restrict__ ws,
                                              float* __restrict__ out,
                                              int t) {
    const int rp = t & 1, wp = rp ^ 1;
    const int bid = blockIdx.x, tid = threadIdx.x;
    __shared__ __align__(16) float sh[8064];   // 32.3KB: conv in-dbuf 2x4032 | fc1 4224 | fc2 4608

    if (bid < 256) {
        // ---- conv3 [0,128) / conv2 [128,256): inputs staged via gll16 into 28-stride LDS ----
        const bool is3 = bid < 128;
        int bb = is3 ? bid : bid - 128;
        int b = bb >> 3, cog = bb & 7;
        int cl = tid >> 5, rest = tid & 31, rpair = rest >> 2, cg = rest & 3;
        int y0 = rpair*2, x0 = cg*4;
        int co = cog*16 + cl*2;
        const int NCI = is3 ? 128 : 64;
        const float* gip = is3 ? (ws + off_o2p + rp*O2PN + b*128*360)
                               : (ws + off_o1p + rp*O1PN + b*64*360);
        const float* wpt = is3 ? (ws + off_w3r + (cog*8 + cl)*128*20)
                               : (ws + off_w2r + (cog*8 + cl)*64*20);
        // staging slot precompute: chunk c -> (u=c/126, r=(c%126)/7, j=(c%126)%7)
        int ssrc[4], sdst[4];
        #pragma unroll
        for (int k = 0; k < 4; ++k) {
            int c = k*256 + tid;
            int u = c/126, rem = c - u*126, r = rem/7, j = rem - r*7;
            ssrc[k] = u*360 + (j < 5 ? 20*r + 4*j : 0);
            sdst[k] = c*4;
        }
        float acc[2][2][4] = {};
        float4 WA[5], WB[5];
        CVW_LOAD(WA, wpt);
        CVW_LOAD(WB, wpt + 20);
        CV_STAGE(0, 0);
        __syncthreads();                     // barrier drains vmcnt -> stage 0 landed
        const int NCH = NCI >> 3;
        #pragma unroll 1
        for (int ch = 0; ch < NCH; ++ch) {
            if (ch + 1 < NCH) CV_STAGE((ch+1)&1, ch+1);   // overlaps with this chunk's FMA
            const float* lb = sh + (ch&1)*4032 + y0*28 + x0;
            // software-pipelined reads: issue next plane's ds_reads BEFORE consuming
            // the current one, so each read hides under ~288 cyc of FMA (reg-neutral:
            // both A/B sets were already live in round 8's schedule).
            float4 IAu[4], IBu[4]; float2 IAv[4], IBv[4];
            CVL_READ(IAu, IAv, lb);                       // u=0
            #pragma unroll 1
            for (int i = 0; i < 4; ++i) {
                int u = i*2;
                int ci = ch*8 + u;
                CVL_READ(IBu, IBv, lb + (u+1)*504);       // read u+1 ahead of FMA(A)
                CV4_FMA(IAu, IAv, WA);
                if (ci + 2 < NCI) CVW_LOAD(WA, wpt + (ci+2)*20);
                if (u + 2 < 8) CVL_READ(IAu, IAv, lb + (u+2)*504);  // read u+2 ahead of FMA(B)
                CV4_FMA(IBu, IBv, WB);
                if (ci + 3 < NCI) CVW_LOAD(WB, wpt + (ci+3)*20);
            }
            __syncthreads();                 // all waves done with buf[ch&1]; stage(ch+1) drained
        }
        if (is3) {
            #pragma unroll
            for (int cc = 0; cc < 2; ++cc) {
                float sp[2][4];
                #pragma unroll
                for (int iy = 0; iy < 2; ++iy)
                    #pragma unroll
                    for (int p = 0; p < 4; ++p) {
                        int gm = off_m3 + ((b*128 + co + cc)*16 + y0 + iy)*16 + x0 + p;
                        float m = ws[gm], o = spk(m);
                        float mn = m + acc[cc][iy][p] - o;
                        ws[gm] = mn;
                        sp[iy][p] = spk(mn);
                    }
                int fbase = off_f + wp*FBN + b*8192 + (co + cc)*64 + (y0>>1)*8 + (x0>>1);
                ws[fbase+0] = (sp[0][0]+sp[0][1]+sp[1][0]+sp[1][1])*0.25f;
                ws[fbase+1] = (sp[0][2]+sp[0][3]+sp[1][2]+sp[1][3])*0.25f;
            }
        } else {
            #pragma unroll
            for (int cc = 0; cc < 2; ++cc) {
                #pragma unroll
                for (int iy = 0; iy < 2; ++iy) {
                    int mbase = off_m2 + ((b*128 + co + cc)*16 + y0 + iy)*16 + x0;
                    int obase = off_o2p + wp*O2PN + ((b*128 + co + cc)*18 + y0 + iy + 1)*20 + x0 + 1;
                    #pragma unroll
                    for (int p = 0; p < 4; ++p) {
                        float m = ws[mbase+p], o = spk(m);
                        float mn = m + acc[cc][iy][p] - o;
                        ws[mbase+p] = mn;
                        ws[obase+p] = spk(mn);
                    }
                }
            }
        }
    } else if (bid < 384) {
        // ---- fc1 8192->1024 + LIF(m4): barrier-free K-loop, acts from L2, 2-deep W prefetch ----
        int jb = bid - 256;
        int w = tid >> 6, l = tid & 63;
        const float* fp = ws + off_f + rp*FBN;
        const float* wb = L1 + (jb*8 + w*2)*8192;
        float acc[2][16] = {};
        float4 wA[2], wB[2];
        #pragma unroll
        for (int jj = 0; jj < 2; ++jj) {
            wA[jj] = ld4(wb + jj*8192 + l*4);
            wB[jj] = ld4(wb + jj*8192 + 256 + l*4);
        }
        for (int c = 0; c < 32; ++c) {
            const float* av = fp + c*256 + l*4;
            #pragma unroll
            for (int b = 0; b < 16; ++b) {
                float4 fv = ld4(av + b*8192);
                acc[0][b] += wA[0].x*fv.x + wA[0].y*fv.y + wA[0].z*fv.z + wA[0].w*fv.w;
                acc[1][b] += wA[1].x*fv.x + wA[1].y*fv.y + wA[1].z*fv.z + wA[1].w*fv.w;
            }
            wA[0] = wB[0]; wA[1] = wB[1];
            if (c < 30) {
                wB[0] = ld4(wb + (c+2)*256 + l*4);
                wB[1] = ld4(wb + 8192 + (c+2)*256 + l*4);
            }
        }
        #pragma unroll
        for (int jj = 0; jj < 2; ++jj)
            #pragma unroll
            for (int b = 0; b < 16; ++b) acc[jj][b] += __shfl_xor(acc[jj][b], 1);
        float* rg = sh + w*1056;
        if ((l & 1) == 0) {
            #pragma unroll
            for (int jj = 0; jj < 2; ++jj)
                #pragma unroll
                for (int b = 0; b < 16; ++b) rg[(l>>1)*33 + jj*16 + b] = acc[jj][b];
        }
        __syncthreads();
        if (tid < 128) {
            int w2 = tid >> 5, r = tid & 31, jj = r >> 4, b = r & 15;
            const float* rg2 = sh + w2*1056;
            float sum = 0.0f;
            #pragma unroll
            for (int l2 = 0; l2 < 32; ++l2) sum += rg2[l2*33 + r];
            int j = jb*8 + w2*2 + jj;
            int gi = off_m4 + b*1024 + j;
            float m = ws[gi], o = spk(m);
            float mn = m + sum - o;
            ws[gi] = mn;
            ws[off_o4 + wp*M4N + b*1024 + j] = spk(mn);
        }
    } else if (bid < 640) {
        // ---- encoder (redundant) + conv1 + LIF(m1) + pooled next-spike ----
        int bb = bid - 384;
        int b = bb >> 4, tile = bb & 15;
        int ty = tile >> 2, tx = tile & 3;
        int y0 = ty*8, x0 = tx*8;
        const float* vin  = ws + off_v + rp*VS + b*3072;
        float*       vout = ws + off_v + wp*VS + b*3072;
        const float* sin_ = ws + off_s + rp*VS + b*3072;
        float*       sout = ws + off_s + wp*VS + b*3072;
        const float* xin  = x + b*3072;
        float* sl = sh; // [3][10][12]
        for (int idx = tid; idx < 300; idx += 256) {
            int ci = idx/100, r2 = idx%100, rr = r2/10, cc = r2%10;
            int yy = y0 - 1 + rr, xx = x0 - 1 + cc;
            float sv = 0.0f;
            if ((unsigned)yy < 32u && (unsigned)xx < 32u) {
                int g = ci*1024 + yy*32 + xx;
                float vn = vin[g] + xin[g] - sin_[g];
                sv = vn > 1.0f ? 1.0f : 0.0f;
                if (yy >= y0 && yy < y0+8 && xx >= x0 && xx < x0+8) { vout[g] = vn; sout[g] = sv; }
            }
            sl[(ci*10 + rr)*12 + cc] = sv;
        }
        __syncthreads();
        int tl = tid & 15, cog = tid >> 4;
        int py = (tl >> 2)*2, px = (tl & 3)*2;
        for (int cl = 0; cl < 4; ++cl) {
            int co = cog*4 + cl;
            const float* wtp = ws + off_w1r + co*36;
            float a00=0,a01=0,a10=0,a11=0;
            #pragma unroll
            for (int ci = 0; ci < 3; ++ci) {
                float4 w0 = ld4(wtp + ci*12), w1 = ld4(wtp + ci*12 + 4), w2 = ld4(wtp + ci*12 + 8);
                float wdl[3][3] = {{w0.x,w0.y,w0.z},{w1.x,w1.y,w1.z},{w2.x,w2.y,w2.z}};
                #pragma unroll
                for (int dy = 0; dy < 3; ++dy)
                    #pragma unroll
                    for (int dx = 0; dx < 3; ++dx) {
                        float wvv = wdl[dy][dx];
                        const float* rsl = sl + (ci*10 + py + dy)*12 + px + dx;
                        a00 += rsl[0]  * wvv; a01 += rsl[1]  * wvv;
                        a10 += rsl[12] * wvv; a11 += rsl[13] * wvv;
                    }
            }
            int gy = y0 + py, gx = x0 + px;
            float accs[2][2] = {{a00,a01},{a10,a11}};
            float pooled = 0.0f;
            #pragma unroll
            for (int iy = 0; iy < 2; ++iy)
                #pragma unroll
                for (int ix = 0; ix < 2; ++ix) {
                    int gm = off_m1 + ((b*64 + co)*32 + gy + iy)*32 + gx + ix;
                    float m = ws[gm], o = spk(m);
                    float mn = m + accs[iy][ix] - o;
                    ws[gm] = mn;
                    pooled += spk(mn);
                }
            ws[off_o1p + wp*O1PN + ((b*64 + co)*18 + (gy>>1) + 1)*20 + (gx>>1) + 1] = pooled*0.25f;
        }
    } else if (bid < 896) {
        // ---- fc2 1024->1024 + LIF(m5); 256 blocks x 4 cols, 64-lane K-split ----
        int jb = bid - 640;
        int jg = tid >> 6, l = tid & 63;
        int j  = jb*4 + jg;
        const float* op = ws + off_o4 + rp*M4N;
        const float* wr = L2 + j*1024;
        float acc[16] = {};
        float4 wv[4];
        #pragma unroll
        for (int u = 0; u < 4; ++u) wv[u] = ld4(wr + u*256 + l*4);
        #pragma unroll
        for (int u = 0; u < 4; ++u) {
            int k = u*256 + l*4;
            #pragma unroll
            for (int b = 0; b < 16; ++b) {
                float4 fv = ld4(op + b*1024 + k);
                acc[b] += wv[u].x*fv.x + wv[u].y*fv.y + wv[u].z*fv.z + wv[u].w*fv.w;
            }
        }
        int r = jg*64 + l;
        #pragma unroll
        for (int b = 0; b < 16; ++b) sh[r*17 + b] = acc[b];
        __syncthreads();
        {
            int p = tid >> 2, q = tid & 3;
            float s2 = 0.0f;
            int rb2 = (p >> 4)*64 + q*16, col = p & 15;
            #pragma unroll
            for (int t2 = 0; t2 < 16; ++t2) s2 += sh[(rb2 + t2)*17 + col];
            sh[4352 + tid] = s2;
        }
        __syncthreads();
        if (tid < 64) {
            float sum = sh[4352 + tid*4] + sh[4352 + tid*4 + 1]
                      + sh[4352 + tid*4 + 2] + sh[4352 + tid*4 + 3];
            int jg2 = tid >> 4, b = tid & 15;
            int jj = jb*4 + jg2;
            int gi = off_m5 + b*1024 + jj;
            float m = ws[gi], o = spk(m);
            float mn = m + sum - o;
            ws[gi] = mn;
            ws[off_o5 + wp*M5N + b*1024 + jj] = spk(mn);
        }
    } else {
        // ---- fc3 1024->10, accumulate output membrane ----
        if (tid < 160) {
            int b = tid/10, c = tid - b*10;
            const float* op = ws + off_o5 + rp*M5N + b*1024;
            const float* wr = L3 + c*1024;
            float sum = 0.0f;
            for (int k = 0; k < 1024; k += 4) {
                float4 a = ld4(op + k), wvv = ld4(wr + k);
                sum += a.x*wvv.x + a.y*wvv.y + a.z*wvv.z + a.w*wvv.w;
            }
            out[b*10 + c] += sum;
        }
    }
}

extern "C" void kernel_launch(void* const* d_in, const int* in_sizes, int n_in,
                              void* d_out, int out_size, void* d_ws, size_t ws_size,
                              hipStream_t stream) {
    const float* x  = (const float*)d_in[0];
    const float* W1 = (const float*)d_in[1];
    const float* W2 = (const float*)d_in[2];
    const float* W3 = (const float*)d_in[3];
    const float* L1 = (const float*)d_in[4];
    const float* L2 = (const float*)d_in[5];
    const float* L3 = (const float*)d_in[6];
    float* out = (float*)d_out;
    float* ws  = (float*)d_ws;

    init_k<<<1024, 256, 0, stream>>>(W1, W2, W3, ws, out);
    for (int t = 0; t < 20; ++t)
        step_k<<<897, 256, 0, stream>>>(x, L1, L2, L3, ws, out, t);
}